// Round 1
// baseline (130.912 us; speedup 1.0000x reference)
//
#include <hip/hip_runtime.h>

// LinearCondensed: out[b,o] = sum_k w[o,k] * x[b, idx[o,k]] + bias[o]
// B=2048, IN_F=4096, OUT_F=4096, K=32, all f32 (idx int32).
//
// Strategy: block stages BT=4 rows of x in LDS (64KB, XOR-swizzled so the
// 4 rows of any column live in 4 distinct banks), then each thread computes
// outputs for one row via LDS gathers. Wave = 4 b-rows x 16 consecutive o.

constexpr int IN_F = 4096;
constexpr int OUT_F = 4096;
constexpr int K = 32;
constexpr int BT = 4;                       // b rows per block (64KB LDS)
constexpr int THREADS = 512;
constexpr int OG = THREADS / BT;            // 128 o-groups per block
constexpr int O_PER_THREAD = OUT_F / OG;    // 32

__global__ __launch_bounds__(THREADS, 4)
void lc_kernel(const float* __restrict__ x,
               const float* __restrict__ w,
               const float* __restrict__ bias,
               const int* __restrict__ idx,
               float* __restrict__ out) {
    __shared__ float xs[BT * IN_F];         // 64 KiB, row r stored with c ^ (8r)
    const int tid = threadIdx.x;
    const int b0 = blockIdx.x * BT;

    // Stage BT rows of x into LDS, float4 loads/stores, per-row XOR swizzle.
    // XOR with {0,8,16,24} only flips bits 3..4 of the element index, so a
    // 4-aligned c stays 4-aligned -> ds_write_b128 stays 16B-aligned, and
    // consecutive lanes still cycle all 32 banks (conflict-free writes).
    const float4* xg = reinterpret_cast<const float4*>(x + (size_t)b0 * IN_F);
#pragma unroll
    for (int it = 0; it < (BT * IN_F / 4) / THREADS; ++it) {
        int i = tid + it * THREADS;
        int r = i >> 10;                    // i / (IN_F/4)
        int c4 = i & 1023;
        float4 v = xg[(size_t)r * (IN_F / 4) + c4];
        int c = c4 << 2;
        *reinterpret_cast<float4*>(&xs[(r << 12) + (c ^ (r << 3))]) = v;
    }
    __syncthreads();

    const int bl = tid & (BT - 1);          // which staged row this thread owns
    const int og = tid >> 2;                // 0..127; wave = 4 b x 16 consecutive o
    const float* __restrict__ xrow = &xs[bl << 12];
    const int swz = bl << 3;
    float* __restrict__ orow = out + (size_t)(b0 + bl) * OUT_F;

#pragma unroll 1
    for (int i = 0; i < O_PER_THREAD; ++i) {
        const int o = og + i * OG;
        const int4* ip = reinterpret_cast<const int4*>(idx + (size_t)o * K);
        const float4* wp = reinterpret_cast<const float4*>(w + (size_t)o * K);
        float acc0 = 0.f, acc1 = 0.f;
#pragma unroll
        for (int kk = 0; kk < K / 4; ++kk) {
            int4 i4 = ip[kk];
            float4 w4 = wp[kk];
            acc0 += w4.x * xrow[i4.x ^ swz];
            acc1 += w4.y * xrow[i4.y ^ swz];
            acc0 += w4.z * xrow[i4.z ^ swz];
            acc1 += w4.w * xrow[i4.w ^ swz];
        }
        orow[o] = acc0 + acc1 + bias[o];
    }
}

extern "C" void kernel_launch(void* const* d_in, const int* in_sizes, int n_in,
                              void* d_out, int out_size, void* d_ws, size_t ws_size,
                              hipStream_t stream) {
    const float* x    = (const float*)d_in[0];
    const float* w    = (const float*)d_in[1];
    const float* bias = (const float*)d_in[2];
    const int*   idx  = (const int*)d_in[3];
    float* out = (float*)d_out;

    const int Bv = in_sizes[0] / IN_F;      // 2048
    lc_kernel<<<dim3(Bv / BT), dim3(THREADS), 0, stream>>>(x, w, bias, idx, out);
}

// Round 2
// 44.330 us; speedup vs baseline: 2.9531x; 2.9531x over previous
//
#include <hip/hip_runtime.h>

// LinearCondensed: out[b,o] = sum_k w[o,k] * x[b, idx[o,k]] + bias[o]
// B=2048, IN_F=4096, OUT_F=4096, K=32, f32 (idx int32).
//
// v2: register-resident idx/w (loaded once per block), row-interleaved LDS
// (xs[c] holds col c of 4 batch rows -> one ds_read_b128 gather feeds 4 rows),
// block loops over 32 batch rows in chunks of 4. Inner loop has ZERO global
// loads on the critical path.

constexpr int IN_F  = 4096;
constexpr int OUT_F = 4096;
constexpr int K     = 32;
constexpr int BT    = 4;                       // batch rows staged per iter
constexpr int THREADS = 512;                   // 1 output column per thread
constexpr int ROWS_PER_BLOCK = 32;
constexpr int ITERS = ROWS_PER_BLOCK / BT;     // 8
constexpr int OCHUNKS = OUT_F / THREADS;       // 8

__global__ __launch_bounds__(THREADS, 4)
void lc_kernel(const float* __restrict__ x,
               const float* __restrict__ w,
               const float* __restrict__ bias,
               const int* __restrict__ idx,
               float* __restrict__ out,
               int bchunks) {
    // xs[c] = {x[rb+0][c], x[rb+1][c], x[rb+2][c], x[rb+3][c]} -- 64 KiB
    __shared__ float4 xs[IN_F];
    const int tid = threadIdx.x;
    // bid = ochunk*bchunks + bchunk: the 8 blocks sharing a given x b-chunk
    // are bid = bchunk + {0,64,...,448} == bchunk (mod 8) -> same XCD -> L2 hits.
    const int ochunk = blockIdx.x / bchunks;
    const int bchunk = blockIdx.x % bchunks;
    const int o = ochunk * THREADS + tid;

    // Load this thread's idx row (pre-shifted to byte offsets) and weight row
    // into registers, once. 32+32 VGPRs.
    int   ao[K];
    float wr[K];
    const int4*   ip = reinterpret_cast<const int4*>(idx + (size_t)o * K);
    const float4* wp = reinterpret_cast<const float4*>(w + (size_t)o * K);
#pragma unroll
    for (int kk = 0; kk < K / 4; ++kk) {
        int4   i4 = ip[kk];
        float4 w4 = wp[kk];
        ao[4*kk+0] = i4.x << 4;  ao[4*kk+1] = i4.y << 4;
        ao[4*kk+2] = i4.z << 4;  ao[4*kk+3] = i4.w << 4;
        wr[4*kk+0] = w4.x;  wr[4*kk+1] = w4.y;
        wr[4*kk+2] = w4.z;  wr[4*kk+3] = w4.w;
    }
    const float bv = bias[o];
    const char* xb = reinterpret_cast<const char*>(xs);

    const int b0 = bchunk * ROWS_PER_BLOCK;
    for (int it = 0; it < ITERS; ++it) {
        const int rb = b0 + it * BT;
        __syncthreads();                        // prev iter's readers done
        // Stage 4 rows, interleaved by column. Scalar loads are coalesced
        // (lane -> consecutive c); b128 writes put 8 lanes per 4-bank group
        // = exactly the 128B/cyc LDS write floor (no conflict penalty).
        const float* xr = x + (size_t)rb * IN_F;
#pragma unroll
        for (int j = 0; j < IN_F / THREADS; ++j) {
            const int c = tid + j * THREADS;
            float4 v;
            v.x = xr[c];
            v.y = xr[c + IN_F];
            v.z = xr[c + 2 * IN_F];
            v.w = xr[c + 3 * IN_F];
            xs[c] = v;
        }
        __syncthreads();

        // Gather + FMA: 32 ds_read_b128, 128 FMAs into 4 row-accumulators.
        // No global loads, addresses precomputed -> pure LDS/VALU pipeline.
        float4 acc = {bv, bv, bv, bv};
#pragma unroll
        for (int k = 0; k < K; ++k) {
            float4 xv = *reinterpret_cast<const float4*>(xb + ao[k]);
            acc.x += wr[k] * xv.x;
            acc.y += wr[k] * xv.y;
            acc.z += wr[k] * xv.z;
            acc.w += wr[k] * xv.w;
        }

        // Coalesced stores: lanes -> consecutive o, 256B per row per wave.
        float* op = out + (size_t)rb * OUT_F + o;
        op[0]         = acc.x;
        op[OUT_F]     = acc.y;
        op[2 * OUT_F] = acc.z;
        op[3 * OUT_F] = acc.w;
    }
}

extern "C" void kernel_launch(void* const* d_in, const int* in_sizes, int n_in,
                              void* d_out, int out_size, void* d_ws, size_t ws_size,
                              hipStream_t stream) {
    const float* x    = (const float*)d_in[0];
    const float* w    = (const float*)d_in[1];
    const float* bias = (const float*)d_in[2];
    const int*   idx  = (const int*)d_in[3];
    float* out = (float*)d_out;

    const int Bv = in_sizes[0] / IN_F;           // 2048
    const int bchunks = Bv / ROWS_PER_BLOCK;     // 64
    lc_kernel<<<dim3(OCHUNKS * bchunks), dim3(THREADS), 0, stream>>>(
        x, w, bias, idx, out, bchunks);
}

// Round 3
// 40.683 us; speedup vs baseline: 3.2179x; 1.0896x over previous
//
#include <hip/hip_runtime.h>

// LinearCondensed: out[b,o] = sum_k w[o,k] * x[b, idx[o,k]] + bias[o]
// B=2048, IN_F=4096, OUT_F=4096, K=32, f32 in/out (idx int32).
//
// v3: x staged in LDS as bf16, 8 rows packed per column (int4 per col) ->
// one ds_read_b128 gathers 8 batch rows. Double-buffered LDS (2x64KB) with
// T14 async-stage split: issue next tile's global loads to registers BEFORE
// the gather loop, convert+ds_write AFTER it, one barrier per iteration.
// Inner loop: 32 ds_read_b128 + 256 unpack/fma, zero exposed memory latency.

constexpr int IN_F  = 4096;
constexpr int OUT_F = 4096;
constexpr int K     = 32;
constexpr int BT    = 8;                     // batch rows per iteration
constexpr int THREADS = 512;                 // 1 output column per thread
constexpr int ROWS_PER_BLOCK = 32;
constexpr int ITERS = ROWS_PER_BLOCK / BT;   // 4
constexpr int CPT = IN_F / THREADS;          // 8 columns staged per thread

__device__ __forceinline__ unsigned pack_bf16(float lo, float hi) {
    // truncate-to-bf16; rel err <= 2^-8, far under tolerance
    return (__float_as_uint(hi) & 0xffff0000u) | (__float_as_uint(lo) >> 16);
}
__device__ __forceinline__ float bf_lo(unsigned u) { return __uint_as_float(u << 16); }
__device__ __forceinline__ float bf_hi(unsigned u) { return __uint_as_float(u & 0xffff0000u); }

__global__ __launch_bounds__(THREADS, 2)
void lc_kernel(const float* __restrict__ x,
               const float* __restrict__ w,
               const float* __restrict__ bias,
               const int* __restrict__ idx,
               float* __restrict__ out,
               int bchunks) {
    // xs[buf][c] = {rows 0..7 of col c, bf16 packed pairs} -- 2 x 64 KiB
    __shared__ int4 xs[2][IN_F];
    const int tid = threadIdx.x;
    // blocks sharing a bchunk are bid = bchunk (mod 8) -> same XCD -> x L2 hits
    const int ochunk = blockIdx.x / bchunks;
    const int bchunk = blockIdx.x % bchunks;
    const int o = ochunk * THREADS + tid;

    // idx (as byte offsets into a 64KB buffer) + weights in registers, once.
    int   ao[K];
    float wr[K];
    const int4*   ip = reinterpret_cast<const int4*>(idx + (size_t)o * K);
    const float4* wp = reinterpret_cast<const float4*>(w + (size_t)o * K);
#pragma unroll
    for (int kk = 0; kk < K / 4; ++kk) {
        int4   i4 = ip[kk];
        float4 w4 = wp[kk];
        ao[4*kk+0] = i4.x << 4;  ao[4*kk+1] = i4.y << 4;
        ao[4*kk+2] = i4.z << 4;  ao[4*kk+3] = i4.w << 4;
        wr[4*kk+0] = w4.x;  wr[4*kk+1] = w4.y;
        wr[4*kk+2] = w4.z;  wr[4*kk+3] = w4.w;
    }
    const float bv = bias[o];
    const int b0 = bchunk * ROWS_PER_BLOCK;

    float pf[BT * CPT];                       // 64 staged values (next tile)

    // ---- prologue: stage tile 0 into buf 0 (latency exposed once) ----
    {
        const float* xr = x + (size_t)b0 * IN_F;
#pragma unroll
        for (int j = 0; j < CPT; ++j)
#pragma unroll
            for (int r = 0; r < BT; ++r)
                pf[j * BT + r] = xr[(size_t)r * IN_F + tid + j * THREADS];
#pragma unroll
        for (int j = 0; j < CPT; ++j) {
            int4 pk;
            pk.x = (int)pack_bf16(pf[j*BT+0], pf[j*BT+1]);
            pk.y = (int)pack_bf16(pf[j*BT+2], pf[j*BT+3]);
            pk.z = (int)pack_bf16(pf[j*BT+4], pf[j*BT+5]);
            pk.w = (int)pack_bf16(pf[j*BT+6], pf[j*BT+7]);
            xs[0][tid + j * THREADS] = pk;
        }
    }
    __syncthreads();

    const char* xb = reinterpret_cast<const char*>(&xs[0][0]);

#pragma unroll
    for (int it = 0; it < ITERS; ++it) {
        const int cur = it & 1;

        // T14 issue-early: next tile's global loads go in flight now,
        // results not touched until after the gather loop below.
        if (it + 1 < ITERS) {
            const float* xr = x + (size_t)(b0 + (it + 1) * BT) * IN_F;
#pragma unroll
            for (int j = 0; j < CPT; ++j)
#pragma unroll
                for (int r = 0; r < BT; ++r)
                    pf[j * BT + r] = xr[(size_t)r * IN_F + tid + j * THREADS];
        }

        // ---- gather + FMA: 32 ds_read_b128, each feeds 8 row-accumulators ----
        float acc[BT];
#pragma unroll
        for (int r = 0; r < BT; ++r) acc[r] = bv;
        const char* xc = xb + cur * (int)sizeof(int4) * IN_F;
#pragma unroll
        for (int k = 0; k < K; ++k) {
            int4 v = *reinterpret_cast<const int4*>(xc + ao[k]);
            const float wk = wr[k];
            acc[0] += wk * bf_lo((unsigned)v.x);
            acc[1] += wk * bf_hi((unsigned)v.x);
            acc[2] += wk * bf_lo((unsigned)v.y);
            acc[3] += wk * bf_hi((unsigned)v.y);
            acc[4] += wk * bf_lo((unsigned)v.z);
            acc[5] += wk * bf_hi((unsigned)v.z);
            acc[6] += wk * bf_lo((unsigned)v.w);
            acc[7] += wk * bf_hi((unsigned)v.w);
        }

        // coalesced stores: 8 rows x 256B per wave
        float* op = out + (size_t)(b0 + it * BT) * OUT_F + o;
#pragma unroll
        for (int r = 0; r < BT; ++r) op[(size_t)r * OUT_F] = acc[r];

        // T14 write-late: convert + ds_write into the other buffer.
        // (vmcnt wait lands here, ~3000 cycles after issue -> fully hidden)
        if (it + 1 < ITERS) {
            int4* xw = &xs[cur ^ 1][0];
#pragma unroll
            for (int j = 0; j < CPT; ++j) {
                int4 pk;
                pk.x = (int)pack_bf16(pf[j*BT+0], pf[j*BT+1]);
                pk.y = (int)pack_bf16(pf[j*BT+2], pf[j*BT+3]);
                pk.z = (int)pack_bf16(pf[j*BT+4], pf[j*BT+5]);
                pk.w = (int)pack_bf16(pf[j*BT+6], pf[j*BT+7]);
                xw[tid + j * THREADS] = pk;
            }
        }
        __syncthreads();
    }
}

extern "C" void kernel_launch(void* const* d_in, const int* in_sizes, int n_in,
                              void* d_out, int out_size, void* d_ws, size_t ws_size,
                              hipStream_t stream) {
    const float* x    = (const float*)d_in[0];
    const float* w    = (const float*)d_in[1];
    const float* bias = (const float*)d_in[2];
    const int*   idx  = (const int*)d_in[3];
    float* out = (float*)d_out;

    const int Bv = in_sizes[0] / IN_F;           // 2048
    const int bchunks = Bv / ROWS_PER_BLOCK;     // 64
    const int ochunks = (in_sizes[1] / K) / THREADS;  // 8
    lc_kernel<<<dim3(ochunks * bchunks), dim3(THREADS), 0, stream>>>(
        x, w, bias, idx, out, bchunks);
}